// Round 9
// baseline (113.244 us; speedup 1.0000x reference)
//
#include <hip/hip_runtime.h>
#include <hip/hip_bf16.h>
#include <stdint.h>

// ChebyKAN: y[b,o] = sum_{i,d} T_d(tanh(x[b,i])) * c[i,o,d]
//   == GEMM [16384 x 4096] x [4096 x 512]  (d=1..8; d=0 via column-sum)
//
// R9: in-register A (R8) + RACE FIX. R8's 3-buffer/1-barrier scheme was
// unsound: vmcnt is per-wave, so waiting AFTER the barrier only certifies
// the wave's own global_load_lds writes; other waves' quarters may land
// late => tripwire divergence. Restored R7's invariant: every wave waits
// vmcnt(4) BEFORE barrier-1, so all quarters of B(s) are in LDS before any
// wave reads. 2 buffers, 2 barriers, counted vmcnt (never 0 in loop).

#define BM 128
#define BN 128
#define NSTEPS 64          // 16 i-tiles * 4 degree-pairs; K-step = 64
#define IN_DIM 512
#define OUT_DIM 512

typedef __attribute__((ext_vector_type(8))) short short8;
typedef __attribute__((ext_vector_type(4))) float f32x4;

__device__ __forceinline__ unsigned short f2bf(float f) {
  __hip_bfloat16 h = __float2bfloat16(f);
  return __builtin_bit_cast(unsigned short, h);
}

__device__ __forceinline__ float fast_tanh(float v) {
  float e = __expf(v + v);
  return 1.0f - 2.0f * __builtin_amdgcn_rcpf(e + 1.0f);
}

__device__ __forceinline__ void gload_lds16(const void* g, void* l) {
  __builtin_amdgcn_global_load_lds(
      (const __attribute__((address_space(1))) unsigned int*)(uintptr_t)g,
      (__attribute__((address_space(3))) unsigned int*)(uintptr_t)l,
      16, 0, 0);
}

// ---------------------------------------------------------------------------
// Kernel 1: coeffs[i][o][d] (f32) -> ws: bf16 B^T chunks, pre-swizzled.
// Chunk (nb, c) with c = itile*4 + p is a 16KB image of LDS tile
// [nl 0..127][128 B]: elem (il, dl) at byte nl*128 + ((dl*64+il*2)^((nl&7)<<4)),
// holding coeff d = 1 + 2p + dl.   (unchanged from R6/R7)
// ---------------------------------------------------------------------------
__global__ __launch_bounds__(256) void cheby_reorder_b(
    const float* __restrict__ coeffs, unsigned char* __restrict__ bws) {
  const int g = blockIdx.x * 256 + threadIdx.x;  // 512*512 threads
  const int i = g & 511;
  const int o = g >> 9;
  const int nb = o >> 7, nl = o & 127;
  const int itile = i >> 5, il = i & 31;
  const float* cp = coeffs + (size_t)i * 4608 + (size_t)o * 9;
  const int swz = (nl & 7) << 4;
#pragma unroll
  for (int p = 0; p < 4; ++p) {
    const size_t base =
        ((size_t)(nb * 64 + itile * 4 + p) << 14) + (size_t)nl * 128;
    *(unsigned short*)(bws + base + ((il * 2) ^ swz)) = f2bf(cp[1 + 2 * p]);
    *(unsigned short*)(bws + base + ((64 + il * 2) ^ swz)) =
        f2bf(cp[2 + 2 * p]);
  }
}

// ---------------------------------------------------------------------------
// Kernel 2: colsum[o] = sum_i coeffs[i][o][0]   (T_0 == 1 contribution)
// ---------------------------------------------------------------------------
__global__ __launch_bounds__(64) void cheby_colsum(
    const float* __restrict__ coeffs, float* __restrict__ cs) {
  const int o = blockIdx.x;
  const int l = threadIdx.x;
  float s = 0.0f;
#pragma unroll
  for (int j = 0; j < 8; ++j)
    s += coeffs[(size_t)(l + j * 64) * 4608 + (size_t)o * 9];
#pragma unroll
  for (int off = 32; off > 0; off >>= 1) s += __shfl_down(s, off, 64);
  if (l == 0) cs[o] = s;
}

// ---------------------------------------------------------------------------
// Kernel 3: fused basis-gen + bf16 MFMA GEMM, in-register A.
// 128x128 tile, 4 waves (wave tile 64x64), 16x16x32 mfma, 4x4 frags.
// ---------------------------------------------------------------------------
__global__ __launch_bounds__(256, 2) void cheby_gemm(
    const float* __restrict__ x, const unsigned char* __restrict__ bws,
    const float* __restrict__ colsum, float* __restrict__ out) {
  const int bid = blockIdx.x;
  const int m0 = (bid >> 2) * BM;
  const int nblk = bid & 3;
  const int n0 = nblk * BN;
  const int tid = threadIdx.x;
  const int lane = tid & 63;
  const int wid = tid >> 6;          // 0..3
  const int wm = (wid >> 1) * 64;
  const int wn = (wid & 1) * 64;
  const int l15 = lane & 15;
  const int lhi = lane >> 4;

  __shared__ __align__(16) unsigned char Bs[2][BN * 128];  // 2 x 16KB

  // per-lane A ownership: rows m0+wm+fm*16+l15 (fm=0..3), i = it*32+lhi*8+j
  const float* xrow[4];
#pragma unroll
  for (int fm = 0; fm < 4; ++fm)
    xrow[fm] = x + (size_t)(m0 + wm + fm * 16 + l15) * IN_DIM + lhi * 8;

  float t2[4][8], Tm1[4][8], Tm2[4][8];
  f32x4 acc[4][4];
#pragma unroll
  for (int a = 0; a < 4; ++a)
#pragma unroll
    for (int b = 0; b < 4; ++b) acc[a][b] = (f32x4){0.f, 0.f, 0.f, 0.f};

  const unsigned char* bchunk0 = bws + ((size_t)(nblk * 64) << 14);
  const int goff = wid * 4096 + lane * 16;

  // ---- prologue: issue B(0) into Bs[0]
  {
    const unsigned char* gsrc = bchunk0 + goff;
    unsigned char* ldst = &Bs[0][0] + wid * 4096;
    gload_lds16(gsrc, ldst);
    gload_lds16(gsrc + 1024, ldst + 1024);
    gload_lds16(gsrc + 2048, ldst + 2048);
    gload_lds16(gsrc + 3072, ldst + 3072);
  }

  for (int s = 0; s < NSTEPS; ++s) {
    const int p = s & 1;
    const int q = s & 3;

    // ---- x loads for this i-tile (issued BEFORE B gloads: oldest in FIFO,
    // retired together with B(s) by the vmcnt(4) below).
    float4 xa[4], xb[4];
    if (q == 0) {
      const int it = s >> 2;
#pragma unroll
      for (int fm = 0; fm < 4; ++fm) {
        const float* xp = xrow[fm] + it * 32;
        xa[fm] = reinterpret_cast<const float4*>(xp)[0];
        xb[fm] = reinterpret_cast<const float4*>(xp)[1];
      }
      __builtin_amdgcn_sched_barrier(0);  // keep x loads ahead of B gloads
    }

    // ---- issue B(s+1) into Bs[p^1] (last iter: dummy re-issue of 63)
    {
      const int snext = (s < NSTEPS - 1) ? s + 1 : NSTEPS - 1;
      const unsigned char* gsrc = bchunk0 + ((size_t)snext << 14) + goff;
      unsigned char* ldst = &Bs[p ^ 1][0] + wid * 4096;
      gload_lds16(gsrc, ldst);
      gload_lds16(gsrc + 1024, ldst + 1024);
      gload_lds16(gsrc + 2048, ldst + 2048);
      gload_lds16(gsrc + 3072, ldst + 3072);
    }

    // ---- A: advance recurrence 2 degrees in-register (pure VALU — overlaps
    // the in-flight loads). After this: Tm2 = T_{1+2q'}, Tm1 = T_{2+2q'}.
    if (q == 0) {
#pragma unroll
      for (int fm = 0; fm < 4; ++fm) {
#pragma unroll
        for (int j = 0; j < 8; ++j) {
          const float xv = (j < 4) ? ((const float*)&xa[fm])[j & 3]
                                   : ((const float*)&xb[fm])[j & 3];
          const float th = fast_tanh(xv);
          const float tt = th + th;
          t2[fm][j] = tt;
          Tm2[fm][j] = th;                               // T_1
          Tm1[fm][j] = __builtin_fmaf(tt, th, -1.0f);    // T_2
        }
      }
    } else {
#pragma unroll
      for (int fm = 0; fm < 4; ++fm) {
#pragma unroll
        for (int j = 0; j < 8; ++j) {
          const float Ta = __builtin_fmaf(t2[fm][j], Tm1[fm][j], -Tm2[fm][j]);
          const float Tb = __builtin_fmaf(t2[fm][j], Ta, -Tm1[fm][j]);
          Tm2[fm][j] = Ta;
          Tm1[fm][j] = Tb;
        }
      }
    }
    // pack A fragments: af0 = T_{d0} (k-slice 0), af1 = T_{d1} (k-slice 1)
    short8 af0[4], af1[4];
#pragma unroll
    for (int fm = 0; fm < 4; ++fm)
#pragma unroll
      for (int j = 0; j < 8; ++j) {
        af0[fm][j] = (short)f2bf(Tm2[fm][j]);
        af1[fm][j] = (short)f2bf(Tm1[fm][j]);
      }

    // ---- cross-wave handshake: THIS wave's B(s) writes (and x loads) are
    // retired BEFORE barrier-1; only the 4 fresh B(s+1) loads stay in
    // flight. After the barrier, every wave's B(s) quarter is in LDS.
    asm volatile("s_waitcnt vmcnt(4)" ::: "memory");
    __builtin_amdgcn_s_barrier();

    // ---- MFMA over B(s) from Bs[p]
    const unsigned char* Bcur = &Bs[p][0];
#pragma unroll
    for (int fn = 0; fn < 4; ++fn) {
      const int row = wn + fn * 16 + l15;
      const int rsw = (row & 7) << 4;
      const short8 bf0 = *(const short8*)(
          Bcur + row * 128 + ((lhi * 16) ^ rsw));
      const short8 bf1 = *(const short8*)(
          Bcur + row * 128 + ((64 + lhi * 16) ^ rsw));
#pragma unroll
      for (int fm = 0; fm < 4; ++fm)
        acc[fm][fn] = __builtin_amdgcn_mfma_f32_16x16x32_bf16(
            af0[fm], bf0, acc[fm][fn], 0, 0, 0);
#pragma unroll
      for (int fm = 0; fm < 4; ++fm)
        acc[fm][fn] = __builtin_amdgcn_mfma_f32_16x16x32_bf16(
            af1[fm], bf1, acc[fm][fn], 0, 0, 0);
    }

    // ---- barrier-2: all reads of Bs[p] done before iter s+1 issues writes
    // into it. No vmcnt drain here (B(s+1) loads stay in flight).
    __builtin_amdgcn_s_barrier();
  }

  // retire the trailing dummy prefetch before the epilogue stores.
  asm volatile("s_waitcnt vmcnt(0)" ::: "memory");

  // ---- epilogue: add d=0 colsum, store f32
  float csv[4];
#pragma unroll
  for (int fn = 0; fn < 4; ++fn) csv[fn] = colsum[n0 + wn + fn * 16 + l15];
  const int lhi4 = lhi * 4;
#pragma unroll
  for (int fm = 0; fm < 4; ++fm) {
    const int r0 = m0 + wm + fm * 16 + lhi4;
#pragma unroll
    for (int fn = 0; fn < 4; ++fn) {
      const int col = n0 + wn + fn * 16 + l15;
#pragma unroll
      for (int r = 0; r < 4; ++r)
        out[(size_t)(r0 + r) * OUT_DIM + col] = acc[fm][fn][r] + csv[fn];
    }
  }
}

extern "C" void kernel_launch(void* const* d_in, const int* in_sizes, int n_in,
                              void* d_out, int out_size, void* d_ws,
                              size_t ws_size, hipStream_t stream) {
  const float* x = (const float*)d_in[0];           // [16384, 512] f32
  const float* coeffs = (const float*)d_in[1];      // [512, 512, 9] f32
  float* out = (float*)d_out;                       // [16384, 512] f32
  unsigned char* bws = (unsigned char*)d_ws;        // 4MB bf16 B tiles
  float* cs = (float*)((unsigned char*)d_ws + ((size_t)4 << 20));  // +2KB

  hipLaunchKernelGGL(cheby_reorder_b, dim3(1024), dim3(256), 0, stream, coeffs,
                     bws);
  hipLaunchKernelGGL(cheby_colsum, dim3(512), dim3(64), 0, stream, coeffs, cs);
  hipLaunchKernelGGL(cheby_gemm, dim3(512), dim3(256), 0, stream, x, bws, cs,
                     out);
}